// Round 1
// baseline (11476.864 us; speedup 1.0000x reference)
//
#include <hip/hip_runtime.h>
#include <stdint.h>

#define NN 50000
#define NE 800000
#define DD 256
#define NL 4

typedef __attribute__((ext_vector_type(8))) short short8_t;   // 8 x bf16
typedef __attribute__((ext_vector_type(4))) float f32x4;

__device__ inline unsigned short f2b(float x) {
    union { float f; uint32_t u; } v; v.f = x;
    uint32_t r = (v.u + 0x7fffu + ((v.u >> 16) & 1u)) >> 16;
    return (unsigned short)r;
}

// ---- zero the stats buffer (512 floats) ----
__global__ void zero_k(float* sums) { sums[threadIdx.x] = 0.f; }

// ---- convert W [L][K][N] fp32 -> Wt [L][N][K] bf16 (transposed for MFMA B staging) ----
__global__ void wconv_k(const float* __restrict__ W, unsigned short* __restrict__ Wt) {
    int idx = blockIdx.x * 256 + threadIdx.x;      // over NL*DD*DD
    int l   = idx >> 16;
    int rem = idx & 0xFFFF;
    int k   = rem >> 8;
    int n   = rem & 255;
    float x = W[(l << 16) + (k << 8) + n];         // coalesced in n
    Wt[(l << 16) + (n << 8) + k] = f2b(x);
}

// ---- r = h (layer 0 init) ----
__global__ void copy_k(const float4* __restrict__ src, float4* __restrict__ dst) {
    int i = blockIdx.x * 256 + threadIdx.x;
    dst[i] = src[i];
}

// ---- scatter: r[dst] += h[src], 64 lanes x float4 per edge, 4 edges/block ----
__global__ void scatter_k(const int* __restrict__ ei, const float* __restrict__ hsrc,
                          int hstride, float* __restrict__ r) {
    int g    = threadIdx.x >> 6;          // wave id in block (uniform per wave)
    int lane = threadIdx.x & 63;
    int e    = blockIdx.x * 4 + g;
    int s = ei[e];
    int d = ei[NE + e];
    const float4 v = *(const float4*)(hsrc + (size_t)s * hstride + lane * 4);
    float* rp = r + (size_t)d * DD + lane * 4;
    atomicAdd(rp + 0, v.x);
    atomicAdd(rp + 1, v.y);
    atomicAdd(rp + 2, v.z);
    atomicAdd(rp + 3, v.w);
}

// ---- GEMM: C[M,256] = op(A)[M,256] @ Wt^T + bias ; AOP=1 applies BN+ReLU to A ----
// 128x128 tile, 4 waves (2x2), 16x16x32 bf16 MFMA, BK=32
template<int AOP>
__global__ void gemm_k(const float* __restrict__ A, const unsigned short* __restrict__ Wt,
                       const float* __restrict__ bias,
                       const float* __restrict__ sc, const float* __restrict__ sh,
                       float* __restrict__ C) {
    __shared__ unsigned short As[128][40];   // [row][k] padded
    __shared__ unsigned short Bs[128][40];   // [col][k] padded
    const int tid   = threadIdx.x;
    const int mbase = blockIdx.x * 128;
    const int nbase = blockIdx.y * 128;
    const int wave  = tid >> 6, lane = tid & 63;
    const int wr = wave >> 1, wc = wave & 1;
    const int l15 = lane & 15, l4 = lane >> 4;

    f32x4 acc[4][4] = {};

    for (int ks = 0; ks < 8; ++ks) {
        const int k0 = ks * 32;
        // stage A tile 128x32 (fp32 -> optional BN+ReLU -> bf16)
        #pragma unroll
        for (int s2 = 0; s2 < 4; ++s2) {
            int q = s2 * 256 + tid;           // 0..1023
            int row = q >> 3, c4 = (q & 7) * 4;
            int grow = mbase + row;
            float4 v = {0.f, 0.f, 0.f, 0.f};
            if (grow < NN) v = *(const float4*)(A + (size_t)grow * DD + k0 + c4);
            if (AOP) {
                float4 a = *(const float4*)(sc + k0 + c4);
                float4 b = *(const float4*)(sh + k0 + c4);
                v.x = fmaxf(v.x * a.x + b.x, 0.f);
                v.y = fmaxf(v.y * a.y + b.y, 0.f);
                v.z = fmaxf(v.z * a.z + b.z, 0.f);
                v.w = fmaxf(v.w * a.w + b.w, 0.f);
            }
            ushort4 u;
            u.x = f2b(v.x); u.y = f2b(v.y); u.z = f2b(v.z); u.w = f2b(v.w);
            *(ushort4*)&As[row][c4] = u;
        }
        // stage B tile 128x32 from Wt (already [N][K] bf16)
        #pragma unroll
        for (int s2 = 0; s2 < 2; ++s2) {
            int q = s2 * 256 + tid;           // 0..511
            int col = q >> 2, seg = (q & 3) * 8;
            uint4 w = *(const uint4*)(Wt + (size_t)(nbase + col) * DD + k0 + seg);
            *(uint4*)&Bs[col][seg] = w;
        }
        __syncthreads();

        short8_t af[4], bf[4];
        #pragma unroll
        for (int mf = 0; mf < 4; ++mf)
            af[mf] = *(const short8_t*)&As[wr * 64 + mf * 16 + l15][l4 * 8];
        #pragma unroll
        for (int nf = 0; nf < 4; ++nf)
            bf[nf] = *(const short8_t*)&Bs[wc * 64 + nf * 16 + l15][l4 * 8];
        #pragma unroll
        for (int mf = 0; mf < 4; ++mf)
            #pragma unroll
            for (int nf = 0; nf < 4; ++nf)
                acc[mf][nf] = __builtin_amdgcn_mfma_f32_16x16x32_bf16(
                    af[mf], bf[nf], acc[mf][nf], 0, 0, 0);
        __syncthreads();
    }

    // epilogue: C/D layout col=lane&15, row=(lane>>4)*4+j (verified m89/m91)
    #pragma unroll
    for (int mf = 0; mf < 4; ++mf) {
        int r0 = mbase + wr * 64 + mf * 16 + l4 * 4;
        #pragma unroll
        for (int nf = 0; nf < 4; ++nf) {
            int col = nbase + wc * 64 + nf * 16 + l15;
            float bs = bias[col];
            #pragma unroll
            for (int j = 0; j < 4; ++j) {
                int row = r0 + j;
                if (row < NN) C[(size_t)row * DD + col] = acc[mf][nf][j] + bs;
            }
        }
    }
}

// ---- column stats: sums[c] += sum(X[:,c]), sums[256+c] += sum(X[:,c]^2) ----
__global__ void stats_k(const float* __restrict__ X, float* __restrict__ sums) {
    int col = threadIdx.x;
    float s = 0.f, s2 = 0.f;
    for (int r = blockIdx.x; r < NN; r += gridDim.x) {
        float x = X[(size_t)r * DD + col];
        s += x; s2 += x * x;
    }
    atomicAdd(&sums[col], s);
    atomicAdd(&sums[DD + col], s2);
}

// ---- column stats of relu(X*sc+sh) (for BN3 over m = relu(BN2(t2))) ----
__global__ void bn_stats_k(const float* __restrict__ X, const float* __restrict__ sc,
                           const float* __restrict__ sh, float* __restrict__ sums) {
    int col = threadIdx.x;
    float a = sc[col], b = sh[col];
    float s = 0.f, s2 = 0.f;
    for (int r = blockIdx.x; r < NN; r += gridDim.x) {
        float x = fmaxf(X[(size_t)r * DD + col] * a + b, 0.f);
        s += x; s2 += x * x;
    }
    atomicAdd(&sums[col], s);
    atomicAdd(&sums[DD + col], s2);
}

// ---- finalize BN: scale/shift from sums; re-zero sums for next use ----
__global__ void fin_k(float* __restrict__ sums, const float* __restrict__ g,
                      const float* __restrict__ b, float* __restrict__ sc,
                      float* __restrict__ sh) {
    int c = threadIdx.x;
    float s = sums[c], s2 = sums[DD + c];
    float mu  = s * (1.f / NN);
    float var = s2 * (1.f / NN) - mu * mu;
    float rstd = rsqrtf(var + 1e-5f);
    float a = rstd * g[c];
    sc[c] = a;
    sh[c] = b[c] - mu * a;
    sums[c] = 0.f; sums[DD + c] = 0.f;
}

// ---- final apply: h = relu(BN3(relu(BN2(t2)))); write r(next layer) + out slice ----
__global__ void final_k(const float4* __restrict__ T2,
                        const float* __restrict__ sc2, const float* __restrict__ sh2,
                        const float* __restrict__ sc3, const float* __restrict__ sh3,
                        float4* __restrict__ Rn, float4* __restrict__ Out, int loff4) {
    int i = blockIdx.x * 256 + threadIdx.x;   // over NN*64 float4s
    int row = i >> 6, c4 = i & 63;
    int c = c4 * 4;
    float4 x = T2[i];
    float4 a2 = *(const float4*)(sc2 + c), b2 = *(const float4*)(sh2 + c);
    float4 a3 = *(const float4*)(sc3 + c), b3 = *(const float4*)(sh3 + c);
    float4 m, h;
    m.x = fmaxf(x.x * a2.x + b2.x, 0.f);
    m.y = fmaxf(x.y * a2.y + b2.y, 0.f);
    m.z = fmaxf(x.z * a2.z + b2.z, 0.f);
    m.w = fmaxf(x.w * a2.w + b2.w, 0.f);
    h.x = fmaxf(m.x * a3.x + b3.x, 0.f);
    h.y = fmaxf(m.y * a3.y + b3.y, 0.f);
    h.z = fmaxf(m.z * a3.z + b3.z, 0.f);
    h.w = fmaxf(m.w * a3.w + b3.w, 0.f);
    Rn[i] = h;
    Out[(size_t)row * 256 + loff4 + c4] = h;   // out row stride = 1024 floats = 256 float4
}

extern "C" void kernel_launch(void* const* d_in, const int* in_sizes, int n_in,
                              void* d_out, int out_size, void* d_ws, size_t ws_size,
                              hipStream_t stream) {
    const float* h_in = (const float*)d_in[0];
    const int*   ei   = (const int*)d_in[1];
    const float* W1   = (const float*)d_in[2];
    const float* b1   = (const float*)d_in[3];
    const float* W2   = (const float*)d_in[4];
    const float* b2   = (const float*)d_in[5];
    const float* g1   = (const float*)d_in[6];
    const float* bb1  = (const float*)d_in[7];
    const float* g2   = (const float*)d_in[8];
    const float* bb2  = (const float*)d_in[9];
    const float* g3   = (const float*)d_in[10];
    const float* bb3  = (const float*)d_in[11];
    float* out = (float*)d_out;

    const size_t SZ = (size_t)NN * DD;           // 12.8M floats
    float* r  = (float*)d_ws;
    float* t1 = r + SZ;
    float* t2 = t1 + SZ;
    unsigned short* Wt1 = (unsigned short*)(t2 + SZ);
    unsigned short* Wt2 = Wt1 + (size_t)NL * DD * DD;
    float* sums = (float*)(Wt2 + (size_t)NL * DD * DD);   // 512 floats
    float* sc1 = sums + 512; float* sh1 = sc1 + DD;
    float* sc2 = sh1 + DD;   float* sh2 = sc2 + DD;
    float* sc3 = sh2 + DD;   float* sh3 = sc3 + DD;

    zero_k<<<1, 512, 0, stream>>>(sums);
    wconv_k<<<1024, 256, 0, stream>>>(W1, Wt1);
    wconv_k<<<1024, 256, 0, stream>>>(W2, Wt2);
    copy_k<<<12500, 256, 0, stream>>>((const float4*)h_in, (float4*)r);

    for (int i = 0; i < NL; ++i) {
        const float* gsrc; int gstride;
        if (i == 0) { gsrc = h_in; gstride = DD; }
        else        { gsrc = out + (size_t)(i - 1) * DD; gstride = NL * DD; }

        scatter_k<<<NE / 4, 256, 0, stream>>>(ei, gsrc, gstride, r);

        gemm_k<0><<<dim3(391, 2), 256, 0, stream>>>(
            r, Wt1 + (size_t)i * DD * DD, b1 + (size_t)i * DD, nullptr, nullptr, t1);
        stats_k<<<1000, 256, 0, stream>>>(t1, sums);
        fin_k<<<1, 256, 0, stream>>>(sums, g1 + (size_t)i * DD, bb1 + (size_t)i * DD, sc1, sh1);

        gemm_k<1><<<dim3(391, 2), 256, 0, stream>>>(
            t1, Wt2 + (size_t)i * DD * DD, b2 + (size_t)i * DD, sc1, sh1, t2);
        stats_k<<<1000, 256, 0, stream>>>(t2, sums);
        fin_k<<<1, 256, 0, stream>>>(sums, g2 + (size_t)i * DD, bb2 + (size_t)i * DD, sc2, sh2);

        bn_stats_k<<<1000, 256, 0, stream>>>(t2, sc2, sh2, sums);
        fin_k<<<1, 256, 0, stream>>>(sums, g3 + (size_t)i * DD, bb3 + (size_t)i * DD, sc3, sh3);

        final_k<<<12500, 256, 0, stream>>>((const float4*)t2, sc2, sh2, sc3, sh3,
                                           (float4*)r, (float4*)out, i * 64);
    }
}

// Round 2
// 1526.805 us; speedup vs baseline: 7.5169x; 7.5169x over previous
//
#include <hip/hip_runtime.h>
#include <stdint.h>

#define NN 50000
#define NE 800000
#define DD 256
#define NL 4

typedef __attribute__((ext_vector_type(8))) short short8_t;   // 8 x bf16
typedef __attribute__((ext_vector_type(4))) float f32x4;

__device__ inline unsigned short f2b(float x) {
    union { float f; uint32_t u; } v; v.f = x;
    uint32_t r = (v.u + 0x7fffu + ((v.u >> 16) & 1u)) >> 16;
    return (unsigned short)r;
}

// ---- zero the stats buffer (512 floats) ----
__global__ void zero_k(float* sums) { sums[threadIdx.x] = 0.f; }

// ---- convert W [L][K][N] fp32 -> Wt [L][N][K] bf16 ----
__global__ void wconv_k(const float* __restrict__ W, unsigned short* __restrict__ Wt) {
    int idx = blockIdx.x * 256 + threadIdx.x;      // over NL*DD*DD
    int l   = idx >> 16;
    int rem = idx & 0xFFFF;
    int k   = rem >> 8;
    int n   = rem & 255;
    float x = W[(l << 16) + (k << 8) + n];
    Wt[(l << 16) + (n << 8) + k] = f2b(x);
}

// ======================= CSR build (once) =======================
__global__ void zdeg_k(int* __restrict__ deg) {
    int i = blockIdx.x * 256 + threadIdx.x;
    if (i < NN) deg[i] = 0;
}

__global__ void hist_k(const int* __restrict__ ei, int* __restrict__ deg) {
    int e = blockIdx.x * 256 + threadIdx.x;
    if (e < NE) atomicAdd(&deg[ei[NE + e]], 1);
}

// single-block exclusive scan over NN degrees -> rowptr, cursor
__global__ void scan_k(const int* __restrict__ deg, int* __restrict__ rowptr,
                       int* __restrict__ cursor) {
    __shared__ int partial[1024];
    const int t = threadIdx.x;
    const int CH = (NN + 1023) / 1024;     // 49
    int base = t * CH;
    int s = 0;
    for (int i = 0; i < CH; ++i) {
        int idx = base + i;
        if (idx < NN) s += deg[idx];
    }
    partial[t] = s;
    __syncthreads();
    for (int off = 1; off < 1024; off <<= 1) {
        int v = (t >= off) ? partial[t - off] : 0;
        __syncthreads();
        partial[t] += v;
        __syncthreads();
    }
    int run = (t == 0) ? 0 : partial[t - 1];
    for (int i = 0; i < CH; ++i) {
        int idx = base + i;
        if (idx < NN) {
            rowptr[idx] = run;
            cursor[idx] = run;
            run += deg[idx];
        }
    }
    if (t == 1023) rowptr[NN] = run;
}

__global__ void fill_k(const int* __restrict__ ei, int* __restrict__ cursor,
                       int* __restrict__ csr) {
    int e = blockIdx.x * 256 + threadIdx.x;
    if (e < NE) {
        int d = ei[NE + e];
        int p = atomicAdd(&cursor[d], 1);
        csr[p] = ei[e];
    }
}

// ======================= per-layer gather =======================
// r[n] = h[n] + sum_{s in adj(n)} h[s] ; one wave per node, lane = float4 slice
__global__ void gather_k(const int* __restrict__ rowptr, const int* __restrict__ csr,
                         const float* __restrict__ hsrc, int hstride,
                         float* __restrict__ r) {
    int w    = threadIdx.x >> 6;
    int lane = threadIdx.x & 63;
    int node = blockIdx.x * 4 + w;
    if (node >= NN) return;
    int beg = rowptr[node], end = rowptr[node + 1];
    int c = lane * 4;
    float4 acc = *(const float4*)(hsrc + (size_t)node * hstride + c);
    int j = beg;
    for (; j + 4 <= end; j += 4) {
        int s0 = csr[j], s1 = csr[j + 1], s2 = csr[j + 2], s3 = csr[j + 3];
        float4 v0 = *(const float4*)(hsrc + (size_t)s0 * hstride + c);
        float4 v1 = *(const float4*)(hsrc + (size_t)s1 * hstride + c);
        float4 v2 = *(const float4*)(hsrc + (size_t)s2 * hstride + c);
        float4 v3 = *(const float4*)(hsrc + (size_t)s3 * hstride + c);
        acc.x += v0.x + v1.x + v2.x + v3.x;
        acc.y += v0.y + v1.y + v2.y + v3.y;
        acc.z += v0.z + v1.z + v2.z + v3.z;
        acc.w += v0.w + v1.w + v2.w + v3.w;
    }
    for (; j < end; ++j) {
        int s0 = csr[j];
        float4 v0 = *(const float4*)(hsrc + (size_t)s0 * hstride + c);
        acc.x += v0.x; acc.y += v0.y; acc.z += v0.z; acc.w += v0.w;
    }
    *(float4*)(r + (size_t)node * DD + c) = acc;
}

// ---- GEMM: C[M,256] = op(A)[M,256] @ Wt^T + bias ; AOP=1 applies BN+ReLU to A ----
template<int AOP>
__global__ void gemm_k(const float* __restrict__ A, const unsigned short* __restrict__ Wt,
                       const float* __restrict__ bias,
                       const float* __restrict__ sc, const float* __restrict__ sh,
                       float* __restrict__ C) {
    __shared__ unsigned short As[128][40];
    __shared__ unsigned short Bs[128][40];
    const int tid   = threadIdx.x;
    const int mbase = blockIdx.x * 128;
    const int nbase = blockIdx.y * 128;
    const int wave  = tid >> 6, lane = tid & 63;
    const int wr = wave >> 1, wc = wave & 1;
    const int l15 = lane & 15, l4 = lane >> 4;

    f32x4 acc[4][4] = {};

    for (int ks = 0; ks < 8; ++ks) {
        const int k0 = ks * 32;
        #pragma unroll
        for (int s2 = 0; s2 < 4; ++s2) {
            int q = s2 * 256 + tid;
            int row = q >> 3, c4 = (q & 7) * 4;
            int grow = mbase + row;
            float4 v = {0.f, 0.f, 0.f, 0.f};
            if (grow < NN) v = *(const float4*)(A + (size_t)grow * DD + k0 + c4);
            if (AOP) {
                float4 a = *(const float4*)(sc + k0 + c4);
                float4 b = *(const float4*)(sh + k0 + c4);
                v.x = fmaxf(v.x * a.x + b.x, 0.f);
                v.y = fmaxf(v.y * a.y + b.y, 0.f);
                v.z = fmaxf(v.z * a.z + b.z, 0.f);
                v.w = fmaxf(v.w * a.w + b.w, 0.f);
            }
            ushort4 u;
            u.x = f2b(v.x); u.y = f2b(v.y); u.z = f2b(v.z); u.w = f2b(v.w);
            *(ushort4*)&As[row][c4] = u;
        }
        #pragma unroll
        for (int s2 = 0; s2 < 2; ++s2) {
            int q = s2 * 256 + tid;
            int col = q >> 2, seg = (q & 3) * 8;
            uint4 w = *(const uint4*)(Wt + (size_t)(nbase + col) * DD + k0 + seg);
            *(uint4*)&Bs[col][seg] = w;
        }
        __syncthreads();

        short8_t af[4], bf[4];
        #pragma unroll
        for (int mf = 0; mf < 4; ++mf)
            af[mf] = *(const short8_t*)&As[wr * 64 + mf * 16 + l15][l4 * 8];
        #pragma unroll
        for (int nf = 0; nf < 4; ++nf)
            bf[nf] = *(const short8_t*)&Bs[wc * 64 + nf * 16 + l15][l4 * 8];
        #pragma unroll
        for (int mf = 0; mf < 4; ++mf)
            #pragma unroll
            for (int nf = 0; nf < 4; ++nf)
                acc[mf][nf] = __builtin_amdgcn_mfma_f32_16x16x32_bf16(
                    af[mf], bf[nf], acc[mf][nf], 0, 0, 0);
        __syncthreads();
    }

    #pragma unroll
    for (int mf = 0; mf < 4; ++mf) {
        int r0 = mbase + wr * 64 + mf * 16 + l4 * 4;
        #pragma unroll
        for (int nf = 0; nf < 4; ++nf) {
            int col = nbase + wc * 64 + nf * 16 + l15;
            float bs = bias[col];
            #pragma unroll
            for (int j = 0; j < 4; ++j) {
                int row = r0 + j;
                if (row < NN) C[(size_t)row * DD + col] = acc[mf][nf][j] + bs;
            }
        }
    }
}

// ---- column stats ----
__global__ void stats_k(const float* __restrict__ X, float* __restrict__ sums) {
    int col = threadIdx.x;
    float s = 0.f, s2 = 0.f;
    for (int r = blockIdx.x; r < NN; r += gridDim.x) {
        float x = X[(size_t)r * DD + col];
        s += x; s2 += x * x;
    }
    atomicAdd(&sums[col], s);
    atomicAdd(&sums[DD + col], s2);
}

__global__ void bn_stats_k(const float* __restrict__ X, const float* __restrict__ sc,
                           const float* __restrict__ sh, float* __restrict__ sums) {
    int col = threadIdx.x;
    float a = sc[col], b = sh[col];
    float s = 0.f, s2 = 0.f;
    for (int r = blockIdx.x; r < NN; r += gridDim.x) {
        float x = fmaxf(X[(size_t)r * DD + col] * a + b, 0.f);
        s += x; s2 += x * x;
    }
    atomicAdd(&sums[col], s);
    atomicAdd(&sums[DD + col], s2);
}

__global__ void fin_k(float* __restrict__ sums, const float* __restrict__ g,
                      const float* __restrict__ b, float* __restrict__ sc,
                      float* __restrict__ sh) {
    int c = threadIdx.x;
    float s = sums[c], s2 = sums[DD + c];
    float mu  = s * (1.f / NN);
    float var = s2 * (1.f / NN) - mu * mu;
    float rstd = rsqrtf(var + 1e-5f);
    float a = rstd * g[c];
    sc[c] = a;
    sh[c] = b[c] - mu * a;
    sums[c] = 0.f; sums[DD + c] = 0.f;
}

// ---- final apply: h = relu(BN3(relu(BN2(t2)))); write out slice ----
__global__ void final_k(const float4* __restrict__ T2,
                        const float* __restrict__ sc2, const float* __restrict__ sh2,
                        const float* __restrict__ sc3, const float* __restrict__ sh3,
                        float4* __restrict__ Out, int loff4) {
    int i = blockIdx.x * 256 + threadIdx.x;   // over NN*64 float4s
    int row = i >> 6, c4 = i & 63;
    int c = c4 * 4;
    float4 x = T2[i];
    float4 a2 = *(const float4*)(sc2 + c), b2 = *(const float4*)(sh2 + c);
    float4 a3 = *(const float4*)(sc3 + c), b3 = *(const float4*)(sh3 + c);
    float4 m, h;
    m.x = fmaxf(x.x * a2.x + b2.x, 0.f);
    m.y = fmaxf(x.y * a2.y + b2.y, 0.f);
    m.z = fmaxf(x.z * a2.z + b2.z, 0.f);
    m.w = fmaxf(x.w * a2.w + b2.w, 0.f);
    h.x = fmaxf(m.x * a3.x + b3.x, 0.f);
    h.y = fmaxf(m.y * a3.y + b3.y, 0.f);
    h.z = fmaxf(m.z * a3.z + b3.z, 0.f);
    h.w = fmaxf(m.w * a3.w + b3.w, 0.f);
    Out[(size_t)row * 256 + loff4 + c4] = h;
}

extern "C" void kernel_launch(void* const* d_in, const int* in_sizes, int n_in,
                              void* d_out, int out_size, void* d_ws, size_t ws_size,
                              hipStream_t stream) {
    const float* h_in = (const float*)d_in[0];
    const int*   ei   = (const int*)d_in[1];
    const float* W1   = (const float*)d_in[2];
    const float* b1   = (const float*)d_in[3];
    const float* W2   = (const float*)d_in[4];
    const float* b2   = (const float*)d_in[5];
    const float* g1   = (const float*)d_in[6];
    const float* bb1  = (const float*)d_in[7];
    const float* g2   = (const float*)d_in[8];
    const float* bb2  = (const float*)d_in[9];
    const float* g3   = (const float*)d_in[10];
    const float* bb3  = (const float*)d_in[11];
    float* out = (float*)d_out;

    const size_t SZ = (size_t)NN * DD;
    float* r  = (float*)d_ws;
    float* t1 = r + SZ;
    float* t2 = t1 + SZ;
    unsigned short* Wt1 = (unsigned short*)(t2 + SZ);
    unsigned short* Wt2 = Wt1 + (size_t)NL * DD * DD;
    float* sums = (float*)(Wt2 + (size_t)NL * DD * DD);   // 512 floats
    float* sc1 = sums + 512; float* sh1 = sc1 + DD;
    float* sc2 = sh1 + DD;   float* sh2 = sc2 + DD;
    float* sc3 = sh2 + DD;   float* sh3 = sc3 + DD;
    int* deg    = (int*)(sh3 + DD);
    int* rowptr = deg + NN;          // NN+1
    int* cursor = rowptr + NN + 1;
    int* csr    = cursor + NN;       // NE

    // one-time setup
    zero_k<<<1, 512, 0, stream>>>(sums);
    wconv_k<<<1024, 256, 0, stream>>>(W1, Wt1);
    wconv_k<<<1024, 256, 0, stream>>>(W2, Wt2);
    zdeg_k<<<(NN + 255) / 256, 256, 0, stream>>>(deg);
    hist_k<<<(NE + 255) / 256, 256, 0, stream>>>(ei, deg);
    scan_k<<<1, 1024, 0, stream>>>(deg, rowptr, cursor);
    fill_k<<<(NE + 255) / 256, 256, 0, stream>>>(ei, cursor, csr);

    for (int i = 0; i < NL; ++i) {
        const float* gsrc; int gstride;
        if (i == 0) { gsrc = h_in; gstride = DD; }
        else        { gsrc = out + (size_t)(i - 1) * DD; gstride = NL * DD; }

        gather_k<<<12500, 256, 0, stream>>>(rowptr, csr, gsrc, gstride, r);

        gemm_k<0><<<dim3(391, 2), 256, 0, stream>>>(
            r, Wt1 + (size_t)i * DD * DD, b1 + (size_t)i * DD, nullptr, nullptr, t1);
        stats_k<<<1000, 256, 0, stream>>>(t1, sums);
        fin_k<<<1, 256, 0, stream>>>(sums, g1 + (size_t)i * DD, bb1 + (size_t)i * DD, sc1, sh1);

        gemm_k<1><<<dim3(391, 2), 256, 0, stream>>>(
            t1, Wt2 + (size_t)i * DD * DD, b2 + (size_t)i * DD, sc1, sh1, t2);
        stats_k<<<1000, 256, 0, stream>>>(t2, sums);
        fin_k<<<1, 256, 0, stream>>>(sums, g2 + (size_t)i * DD, bb2 + (size_t)i * DD, sc2, sh2);

        bn_stats_k<<<1000, 256, 0, stream>>>(t2, sc2, sh2, sums);
        fin_k<<<1, 256, 0, stream>>>(sums, g3 + (size_t)i * DD, bb3 + (size_t)i * DD, sc3, sh3);

        final_k<<<12500, 256, 0, stream>>>((const float4*)t2, sc2, sh2, sc3, sh3,
                                           (float4*)out, i * 64);
    }
}

// Round 4
// 1244.937 us; speedup vs baseline: 9.2188x; 1.2264x over previous
//
#include <hip/hip_runtime.h>
#include <stdint.h>

#define NN 50000
#define NPAD 50048          // 391*128, zero-padded rows for GEMM1 A-tile
#define NE 800000
#define DD 256
#define NL 4

typedef __attribute__((ext_vector_type(8))) _Float16 half8;
typedef __attribute__((ext_vector_type(4))) float f32x4;

__device__ inline unsigned short f2h(float x) {
    union { _Float16 h; unsigned short u; } v;
    v.h = (_Float16)x;
    return v.u;
}

// ---- zero the stats buffer (512 floats) ----
__global__ void zero_k(float* sums) { sums[threadIdx.x] = 0.f; }

// ---- convert W [L][K][N] fp32 -> Wt [L][N][K] fp16 ----
__global__ void wconv_k(const float* __restrict__ W, unsigned short* __restrict__ Wt) {
    int idx = blockIdx.x * 256 + threadIdx.x;
    int l   = idx >> 16;
    int rem = idx & 0xFFFF;
    int k   = rem >> 8;
    int n   = rem & 255;
    float x = W[(l << 16) + (k << 8) + n];
    Wt[(l << 16) + (n << 8) + k] = f2h(x);
}

// ======================= CSR build (once) =======================
__global__ void zdeg_k(int* __restrict__ deg) {
    int i = blockIdx.x * 256 + threadIdx.x;
    if (i < NN) deg[i] = 0;
}

__global__ void hist_k(const int* __restrict__ ei, int* __restrict__ deg) {
    int e = blockIdx.x * 256 + threadIdx.x;
    if (e < NE) atomicAdd(&deg[ei[NE + e]], 1);
}

// phase 1: per-block sums of deg (196 blocks x 256)
__global__ void bsum_k(const int* __restrict__ deg, int* __restrict__ bsum) {
    __shared__ int sm[256];
    int i = blockIdx.x * 256 + threadIdx.x;
    sm[threadIdx.x] = (i < NN) ? deg[i] : 0;
    __syncthreads();
    for (int off = 128; off > 0; off >>= 1) {
        if (threadIdx.x < off) sm[threadIdx.x] += sm[threadIdx.x + off];
        __syncthreads();
    }
    if (threadIdx.x == 0) bsum[blockIdx.x] = sm[0];
}

// phase 2: exclusive scan of 196 block sums (1 block)
__global__ void bscan_k(const int* __restrict__ bsum, int* __restrict__ boff) {
    __shared__ int sm[256];
    int t = threadIdx.x;
    int v = (t < 196) ? bsum[t] : 0;
    sm[t] = v; __syncthreads();
    for (int off = 1; off < 256; off <<= 1) {
        int u = (t >= off) ? sm[t - off] : 0;
        __syncthreads();
        sm[t] += u;
        __syncthreads();
    }
    boff[t] = sm[t] - v;
}

// phase 3: local exclusive scan + global offset -> rowptr, cursor
__global__ void rowptr_k(const int* __restrict__ deg, const int* __restrict__ boff,
                         int* __restrict__ rowptr, int* __restrict__ cursor) {
    __shared__ int sm[256];
    int b = blockIdx.x, t = threadIdx.x;
    int i = b * 256 + t;
    int v = (i < NN) ? deg[i] : 0;
    sm[t] = v; __syncthreads();
    for (int off = 1; off < 256; off <<= 1) {
        int u = (t >= off) ? sm[t - off] : 0;
        __syncthreads();
        sm[t] += u;
        __syncthreads();
    }
    int excl = boff[b] + sm[t] - v;
    if (i < NN) { rowptr[i] = excl; cursor[i] = excl; }
    if (i == NN - 1) rowptr[NN] = excl + v;
}

__global__ void fill_k(const int* __restrict__ ei, int* __restrict__ cursor,
                       int* __restrict__ csr) {
    int e = blockIdx.x * 256 + threadIdx.x;
    if (e < NE) {
        int d = ei[NE + e];
        int p = atomicAdd(&cursor[d], 1);
        csr[p] = ei[e];
    }
}

// ======================= per-layer gather =======================
// rb[n] = fp16(h[n] + sum_{s in adj(n)} h[s]); rows NN..NPAD-1 zeroed
__global__ void gather_k(const int* __restrict__ rowptr, const int* __restrict__ csr,
                         const float* __restrict__ hsrc, int hstride,
                         unsigned short* __restrict__ rb) {
    int w    = threadIdx.x >> 6;
    int lane = threadIdx.x & 63;
    int node = blockIdx.x * 4 + w;
    if (node >= NPAD) return;
    int c = lane * 4;
    unsigned short* dst = rb + (size_t)node * DD + c;
    if (node >= NN) {
        ushort4 z; z.x = 0; z.y = 0; z.z = 0; z.w = 0;
        *(ushort4*)dst = z;
        return;
    }
    int beg = rowptr[node], end = rowptr[node + 1];
    float4 acc = *(const float4*)(hsrc + (size_t)node * hstride + c);
    int j = beg;
    for (; j + 4 <= end; j += 4) {
        int s0 = csr[j], s1 = csr[j + 1], s2 = csr[j + 2], s3 = csr[j + 3];
        float4 v0 = *(const float4*)(hsrc + (size_t)s0 * hstride + c);
        float4 v1 = *(const float4*)(hsrc + (size_t)s1 * hstride + c);
        float4 v2 = *(const float4*)(hsrc + (size_t)s2 * hstride + c);
        float4 v3 = *(const float4*)(hsrc + (size_t)s3 * hstride + c);
        acc.x += v0.x + v1.x + v2.x + v3.x;
        acc.y += v0.y + v1.y + v2.y + v3.y;
        acc.z += v0.z + v1.z + v2.z + v3.z;
        acc.w += v0.w + v1.w + v2.w + v3.w;
    }
    for (; j < end; ++j) {
        int s0 = csr[j];
        float4 v0 = *(const float4*)(hsrc + (size_t)s0 * hstride + c);
        acc.x += v0.x; acc.y += v0.y; acc.z += v0.z; acc.w += v0.w;
    }
    ushort4 u;
    u.x = f2h(acc.x); u.y = f2h(acc.y); u.z = f2h(acc.z); u.w = f2h(acc.w);
    *(ushort4*)dst = u;
}

// =================== GEMM 128x256 tile, 8 waves (2x4), BK=32, fp16 MFMA ===================
// Shared epilogue: C = acc + bias (fp32 store), fused column stats into sums.
#define GEMM_EPILOGUE()                                                          \
    _Pragma("unroll")                                                            \
    for (int nf = 0; nf < 4; ++nf) {                                             \
        int col = wc * 64 + nf * 16 + l15;                                       \
        float bs = bias[col];                                                    \
        float s = 0.f, s2 = 0.f;                                                 \
        _Pragma("unroll")                                                        \
        for (int mf = 0; mf < 4; ++mf) {                                         \
            int r0 = mbase + wr * 64 + mf * 16 + l4 * 4;                         \
            _Pragma("unroll")                                                    \
            for (int j = 0; j < 4; ++j) {                                        \
                int row = r0 + j;                                                \
                if (row < NN) {                                                  \
                    float cv = acc[mf][nf][j] + bs;                              \
                    C[(size_t)row * DD + col] = cv;                              \
                    s += cv; s2 += cv * cv;                                      \
                }                                                                \
            }                                                                    \
        }                                                                        \
        s  += __shfl_xor(s, 16);  s  += __shfl_xor(s, 32);                       \
        s2 += __shfl_xor(s2, 16); s2 += __shfl_xor(s2, 32);                      \
        if (l4 == 0) {                                                           \
            atomicAdd(&sums[col], s);                                            \
            atomicAdd(&sums[DD + col], s2);                                      \
        }                                                                        \
    }

// GEMM1: A already fp16 (rb, zero-padded rows), t1 = A @ Wt^T + b ; stats fused
__global__ void gemm_f16_k(const unsigned short* __restrict__ A,
                           const unsigned short* __restrict__ Wt,
                           const float* __restrict__ bias,
                           float* __restrict__ C, float* __restrict__ sums) {
    __shared__ unsigned short As[128][40];
    __shared__ unsigned short Bs[256][40];
    const int tid   = threadIdx.x;
    const int mbase = blockIdx.x * 128;
    const int wave  = tid >> 6, lane = tid & 63;
    const int wr = wave >> 2, wc = wave & 3;
    const int l15 = lane & 15, l4 = lane >> 4;

    f32x4 acc[4][4] = {};

    for (int ks = 0; ks < 8; ++ks) {
        const int k0 = ks * 32;
        // A: 128x32 fp16 = 8KB = 512 threads x 16B
        {
            int row = tid >> 2, seg = (tid & 3) * 8;
            uint4 wv = *(const uint4*)(A + (size_t)(mbase + row) * DD + k0 + seg);
            *(uint4*)&As[row][seg] = wv;
        }
        // B: 256x32 fp16 = 16KB = 512 threads x 2 x 16B
        #pragma unroll
        for (int sI = 0; sI < 2; ++sI) {
            int q = sI * 512 + tid;
            int col = q >> 2, seg = (q & 3) * 8;
            uint4 wv = *(const uint4*)(Wt + (size_t)col * DD + k0 + seg);
            *(uint4*)&Bs[col][seg] = wv;
        }
        __syncthreads();

        half8 af[4], bf[4];
        #pragma unroll
        for (int mf = 0; mf < 4; ++mf)
            af[mf] = *(const half8*)&As[wr * 64 + mf * 16 + l15][l4 * 8];
        #pragma unroll
        for (int nf = 0; nf < 4; ++nf)
            bf[nf] = *(const half8*)&Bs[wc * 64 + nf * 16 + l15][l4 * 8];
        #pragma unroll
        for (int mf = 0; mf < 4; ++mf)
            #pragma unroll
            for (int nf = 0; nf < 4; ++nf)
                acc[mf][nf] = __builtin_amdgcn_mfma_f32_16x16x32_f16(
                    af[mf], bf[nf], acc[mf][nf], 0, 0, 0);
        __syncthreads();
    }
    GEMM_EPILOGUE()
}

// GEMM2: A fp32 with BN+ReLU applied at staging; t2 = relu(BN(A)) @ Wt^T + b ; stats fused
__global__ void gemm_bn_k(const float* __restrict__ A,
                          const unsigned short* __restrict__ Wt,
                          const float* __restrict__ bias,
                          const float* __restrict__ sc, const float* __restrict__ sh,
                          float* __restrict__ C, float* __restrict__ sums) {
    __shared__ unsigned short As[128][40];
    __shared__ unsigned short Bs[256][40];
    const int tid   = threadIdx.x;
    const int mbase = blockIdx.x * 128;
    const int wave  = tid >> 6, lane = tid & 63;
    const int wr = wave >> 2, wc = wave & 3;
    const int l15 = lane & 15, l4 = lane >> 4;

    f32x4 acc[4][4] = {};

    for (int ks = 0; ks < 8; ++ks) {
        const int k0 = ks * 32;
        // A: 128x32 fp32 -> BN+ReLU -> fp16; 4096 floats = 512 threads x 2 float4
        #pragma unroll
        for (int sI = 0; sI < 2; ++sI) {
            int q = sI * 512 + tid;
            int row = q >> 3, c4 = (q & 7) * 4;
            int grow = mbase + row;
            float4 v = {0.f, 0.f, 0.f, 0.f};
            if (grow < NN) v = *(const float4*)(A + (size_t)grow * DD + k0 + c4);
            float4 a = *(const float4*)(sc + k0 + c4);
            float4 b = *(const float4*)(sh + k0 + c4);
            v.x = fmaxf(v.x * a.x + b.x, 0.f);
            v.y = fmaxf(v.y * a.y + b.y, 0.f);
            v.z = fmaxf(v.z * a.z + b.z, 0.f);
            v.w = fmaxf(v.w * a.w + b.w, 0.f);
            ushort4 u;
            u.x = f2h(v.x); u.y = f2h(v.y); u.z = f2h(v.z); u.w = f2h(v.w);
            *(ushort4*)&As[row][c4] = u;
        }
        #pragma unroll
        for (int sI = 0; sI < 2; ++sI) {
            int q = sI * 512 + tid;
            int col = q >> 2, seg = (q & 3) * 8;
            uint4 wv = *(const uint4*)(Wt + (size_t)col * DD + k0 + seg);
            *(uint4*)&Bs[col][seg] = wv;
        }
        __syncthreads();

        half8 af[4], bf[4];
        #pragma unroll
        for (int mf = 0; mf < 4; ++mf)
            af[mf] = *(const half8*)&As[wr * 64 + mf * 16 + l15][l4 * 8];
        #pragma unroll
        for (int nf = 0; nf < 4; ++nf)
            bf[nf] = *(const half8*)&Bs[wc * 64 + nf * 16 + l15][l4 * 8];
        #pragma unroll
        for (int mf = 0; mf < 4; ++mf)
            #pragma unroll
            for (int nf = 0; nf < 4; ++nf)
                acc[mf][nf] = __builtin_amdgcn_mfma_f32_16x16x32_f16(
                    af[mf], bf[nf], acc[mf][nf], 0, 0, 0);
        __syncthreads();
    }
    GEMM_EPILOGUE()
}

// ---- BN3 stats over m = relu(X*sc+sh), vectorized float4 ----
__global__ void bn_stats_k(const float4* __restrict__ X4, const float* __restrict__ sc,
                           const float* __restrict__ sh, float* __restrict__ sums) {
    __shared__ float4 sA[256];
    __shared__ float4 sB[256];
    int t  = threadIdx.x;
    int rs = t >> 6;           // 0..3
    int c4 = t & 63;
    int c  = c4 * 4;
    float4 a = *(const float4*)(sc + c), b = *(const float4*)(sh + c);
    float4 s = {0.f,0.f,0.f,0.f}, s2 = {0.f,0.f,0.f,0.f};
    for (int r4 = blockIdx.x; r4 < NN / 4; r4 += gridDim.x) {
        int row = r4 * 4 + rs;
        float4 x = X4[(size_t)row * 64 + c4];
        float4 m;
        m.x = fmaxf(x.x * a.x + b.x, 0.f);
        m.y = fmaxf(x.y * a.y + b.y, 0.f);
        m.z = fmaxf(x.z * a.z + b.z, 0.f);
        m.w = fmaxf(x.w * a.w + b.w, 0.f);
        s.x += m.x; s.y += m.y; s.z += m.z; s.w += m.w;
        s2.x += m.x*m.x; s2.y += m.y*m.y; s2.z += m.z*m.z; s2.w += m.w*m.w;
    }
    sA[t] = s; sB[t] = s2;
    __syncthreads();
    if (t < 128) {
        sA[t].x += sA[t+128].x; sA[t].y += sA[t+128].y; sA[t].z += sA[t+128].z; sA[t].w += sA[t+128].w;
        sB[t].x += sB[t+128].x; sB[t].y += sB[t+128].y; sB[t].z += sB[t+128].z; sB[t].w += sB[t+128].w;
    }
    __syncthreads();
    if (t < 64) {
        float4 fs, fs2;
        fs.x = sA[t].x + sA[t+64].x; fs.y = sA[t].y + sA[t+64].y;
        fs.z = sA[t].z + sA[t+64].z; fs.w = sA[t].w + sA[t+64].w;
        fs2.x = sB[t].x + sB[t+64].x; fs2.y = sB[t].y + sB[t+64].y;
        fs2.z = sB[t].z + sB[t+64].z; fs2.w = sB[t].w + sB[t+64].w;
        atomicAdd(&sums[c + 0], fs.x);  atomicAdd(&sums[c + 1], fs.y);
        atomicAdd(&sums[c + 2], fs.z);  atomicAdd(&sums[c + 3], fs.w);
        atomicAdd(&sums[DD + c + 0], fs2.x); atomicAdd(&sums[DD + c + 1], fs2.y);
        atomicAdd(&sums[DD + c + 2], fs2.z); atomicAdd(&sums[DD + c + 3], fs2.w);
    }
}

// ---- finalize BN: scale/shift from sums; re-zero sums ----
__global__ void fin_k(float* __restrict__ sums, const float* __restrict__ g,
                      const float* __restrict__ b, float* __restrict__ sc,
                      float* __restrict__ sh) {
    int c = threadIdx.x;
    float s = sums[c], s2 = sums[DD + c];
    float mu  = s * (1.f / NN);
    float var = s2 * (1.f / NN) - mu * mu;
    float rstd = rsqrtf(var + 1e-5f);
    float a = rstd * g[c];
    sc[c] = a;
    sh[c] = b[c] - mu * a;
    sums[c] = 0.f; sums[DD + c] = 0.f;
}

// ---- final apply: h = relu(BN3(relu(BN2(t2)))); write out slice ----
__global__ void final_k(const float4* __restrict__ T2,
                        const float* __restrict__ sc2, const float* __restrict__ sh2,
                        const float* __restrict__ sc3, const float* __restrict__ sh3,
                        float4* __restrict__ Out, int loff4) {
    int i = blockIdx.x * 256 + threadIdx.x;
    int row = i >> 6, c4 = i & 63;
    int c = c4 * 4;
    float4 x = T2[i];
    float4 a2 = *(const float4*)(sc2 + c), b2 = *(const float4*)(sh2 + c);
    float4 a3 = *(const float4*)(sc3 + c), b3 = *(const float4*)(sh3 + c);
    float4 m, h;
    m.x = fmaxf(x.x * a2.x + b2.x, 0.f);
    m.y = fmaxf(x.y * a2.y + b2.y, 0.f);
    m.z = fmaxf(x.z * a2.z + b2.z, 0.f);
    m.w = fmaxf(x.w * a2.w + b2.w, 0.f);
    h.x = fmaxf(m.x * a3.x + b3.x, 0.f);
    h.y = fmaxf(m.y * a3.y + b3.y, 0.f);
    h.z = fmaxf(m.z * a3.z + b3.z, 0.f);
    h.w = fmaxf(m.w * a3.w + b3.w, 0.f);
    Out[(size_t)row * 256 + loff4 + c4] = h;
}

extern "C" void kernel_launch(void* const* d_in, const int* in_sizes, int n_in,
                              void* d_out, int out_size, void* d_ws, size_t ws_size,
                              hipStream_t stream) {
    const float* h_in = (const float*)d_in[0];
    const int*   ei   = (const int*)d_in[1];
    const float* W1   = (const float*)d_in[2];
    const float* b1   = (const float*)d_in[3];
    const float* W2   = (const float*)d_in[4];
    const float* b2   = (const float*)d_in[5];
    const float* g1   = (const float*)d_in[6];
    const float* bb1  = (const float*)d_in[7];
    const float* g2   = (const float*)d_in[8];
    const float* bb2  = (const float*)d_in[9];
    const float* g3   = (const float*)d_in[10];
    const float* bb3  = (const float*)d_in[11];
    float* out = (float*)d_out;

    const size_t SZ = (size_t)NN * DD;
    float* t1 = (float*)d_ws;
    float* t2 = t1 + SZ;
    unsigned short* rb  = (unsigned short*)(t2 + SZ);          // NPAD*DD fp16
    unsigned short* Wt1 = rb + (size_t)NPAD * DD;
    unsigned short* Wt2 = Wt1 + (size_t)NL * DD * DD;
    float* sums = (float*)(Wt2 + (size_t)NL * DD * DD);        // 512
    float* sc1 = sums + 512; float* sh1 = sc1 + DD;
    float* sc2 = sh1 + DD;   float* sh2 = sc2 + DD;
    float* sc3 = sh2 + DD;   float* sh3 = sc3 + DD;
    int* deg    = (int*)(sh3 + DD);
    int* bsum   = deg + NN;          // 196 (pad 256)
    int* boff   = bsum + 256;        // 256
    int* rowptr = boff + 256;        // NN+1
    int* cursor = rowptr + NN + 1;   // NN
    int* csr    = cursor + NN;       // NE

    // one-time setup
    zero_k<<<1, 512, 0, stream>>>(sums);
    wconv_k<<<1024, 256, 0, stream>>>(W1, Wt1);
    wconv_k<<<1024, 256, 0, stream>>>(W2, Wt2);
    zdeg_k<<<196, 256, 0, stream>>>(deg);
    hist_k<<<(NE + 255) / 256, 256, 0, stream>>>(ei, deg);
    bsum_k<<<196, 256, 0, stream>>>(deg, bsum);
    bscan_k<<<1, 256, 0, stream>>>(bsum, boff);
    rowptr_k<<<196, 256, 0, stream>>>(deg, boff, rowptr, cursor);
    fill_k<<<(NE + 255) / 256, 256, 0, stream>>>(ei, cursor, csr);

    for (int i = 0; i < NL; ++i) {
        const float* gsrc; int gstride;
        if (i == 0) { gsrc = h_in; gstride = DD; }
        else        { gsrc = out + (size_t)(i - 1) * DD; gstride = NL * DD; }

        gather_k<<<NPAD / 4, 256, 0, stream>>>(rowptr, csr, gsrc, gstride, rb);

        gemm_f16_k<<<391, 512, 0, stream>>>(
            rb, Wt1 + (size_t)i * DD * DD, b1 + (size_t)i * DD, t1, sums);
        fin_k<<<1, 256, 0, stream>>>(sums, g1 + (size_t)i * DD, bb1 + (size_t)i * DD, sc1, sh1);

        gemm_bn_k<<<391, 512, 0, stream>>>(
            t1, Wt2 + (size_t)i * DD * DD, b2 + (size_t)i * DD, sc1, sh1, t2, sums);
        fin_k<<<1, 256, 0, stream>>>(sums, g2 + (size_t)i * DD, bb2 + (size_t)i * DD, sc2, sh2);

        bn_stats_k<<<500, 256, 0, stream>>>((const float4*)t2, sc2, sh2, sums);
        fin_k<<<1, 256, 0, stream>>>(sums, g3 + (size_t)i * DD, bb3 + (size_t)i * DD, sc3, sh3);

        final_k<<<12500, 256, 0, stream>>>((const float4*)t2, sc2, sh2, sc3, sh3,
                                           (float4*)out, i * 64);
    }
}

// Round 5
// 1001.093 us; speedup vs baseline: 11.4643x; 1.2436x over previous
//
#include <hip/hip_runtime.h>
#include <stdint.h>

#define NN 50000
#define NPAD 50048          // 391*128, zero-padded rows for GEMM1 A-tile
#define NE 800000
#define DD 256
#define NL 4

typedef __attribute__((ext_vector_type(8))) _Float16 half8;
typedef __attribute__((ext_vector_type(4))) float f32x4;

__device__ inline unsigned short f2h(float x) {
    union { _Float16 h; unsigned short u; } v;
    v.h = (_Float16)x;
    return v.u;
}
__device__ inline float h2f(unsigned short u) {
    union { unsigned short u; _Float16 h; } v;
    v.u = u;
    return (float)v.h;
}

// ---- zero the stats buffer (512 floats) ----
__global__ void zero_k(float* sums) { sums[threadIdx.x] = 0.f; }

// ---- convert W [L][K][N] fp32 -> Wt [L][N][K] fp16 ----
__global__ void wconv_k(const float* __restrict__ W, unsigned short* __restrict__ Wt) {
    int idx = blockIdx.x * 256 + threadIdx.x;
    int l   = idx >> 16;
    int rem = idx & 0xFFFF;
    int k   = rem >> 8;
    int n   = rem & 255;
    float x = W[(l << 16) + (k << 8) + n];
    Wt[(l << 16) + (n << 8) + k] = f2h(x);
}

// ---- convert h_in fp32 -> h16 fp16 (layer 0 only) ----
__global__ void h16conv_k(const float4* __restrict__ H, unsigned short* __restrict__ h16) {
    int i = blockIdx.x * 256 + threadIdx.x;    // over NN*64
    float4 v = H[i];
    ushort4 u;
    u.x = f2h(v.x); u.y = f2h(v.y); u.z = f2h(v.z); u.w = f2h(v.w);
    *(ushort4*)(h16 + (size_t)i * 4) = u;
}

// ======================= CSR build (once) =======================
__global__ void zdeg_k(int* __restrict__ deg) {
    int i = blockIdx.x * 256 + threadIdx.x;
    if (i < NN) deg[i] = 0;
}

__global__ void hist_k(const int* __restrict__ ei, int* __restrict__ deg) {
    int e = blockIdx.x * 256 + threadIdx.x;
    if (e < NE) atomicAdd(&deg[ei[NE + e]], 1);
}

// phase 1: per-block sums of deg (196 blocks x 256)
__global__ void bsum_k(const int* __restrict__ deg, int* __restrict__ bsum) {
    __shared__ int sm[256];
    int i = blockIdx.x * 256 + threadIdx.x;
    sm[threadIdx.x] = (i < NN) ? deg[i] : 0;
    __syncthreads();
    for (int off = 128; off > 0; off >>= 1) {
        if (threadIdx.x < off) sm[threadIdx.x] += sm[threadIdx.x + off];
        __syncthreads();
    }
    if (threadIdx.x == 0) bsum[blockIdx.x] = sm[0];
}

// phase 2: exclusive scan of 196 block sums (1 block)
__global__ void bscan_k(const int* __restrict__ bsum, int* __restrict__ boff) {
    __shared__ int sm[256];
    int t = threadIdx.x;
    int v = (t < 196) ? bsum[t] : 0;
    sm[t] = v; __syncthreads();
    for (int off = 1; off < 256; off <<= 1) {
        int u = (t >= off) ? sm[t - off] : 0;
        __syncthreads();
        sm[t] += u;
        __syncthreads();
    }
    boff[t] = sm[t] - v;
}

// phase 3: local exclusive scan + global offset -> rowptr, cursor
__global__ void rowptr_k(const int* __restrict__ deg, const int* __restrict__ boff,
                         int* __restrict__ rowptr, int* __restrict__ cursor) {
    __shared__ int sm[256];
    int b = blockIdx.x, t = threadIdx.x;
    int i = b * 256 + t;
    int v = (i < NN) ? deg[i] : 0;
    sm[t] = v; __syncthreads();
    for (int off = 1; off < 256; off <<= 1) {
        int u = (t >= off) ? sm[t - off] : 0;
        __syncthreads();
        sm[t] += u;
        __syncthreads();
    }
    int excl = boff[b] + sm[t] - v;
    if (i < NN) { rowptr[i] = excl; cursor[i] = excl; }
    if (i == NN - 1) rowptr[NN] = excl + v;
}

__global__ void fill_k(const int* __restrict__ ei, int* __restrict__ cursor,
                       int* __restrict__ csr) {
    int e = blockIdx.x * 256 + threadIdx.x;
    if (e < NE) {
        int d = ei[NE + e];
        int p = atomicAdd(&cursor[d], 1);
        csr[p] = ei[e];
    }
}

// ======================= per-layer gather (fp16 source) =======================
// rb[n] = fp16(h16[n] + sum_{s in adj(n)} h16[s]); rows NN..NPAD-1 zeroed
__global__ void gather_k(const int* __restrict__ rowptr, const int* __restrict__ csr,
                         const unsigned short* __restrict__ h16,
                         unsigned short* __restrict__ rb) {
    int w    = threadIdx.x >> 6;
    int lane = threadIdx.x & 63;
    int node = blockIdx.x * 4 + w;
    if (node >= NPAD) return;
    int c = lane * 4;
    unsigned short* dst = rb + (size_t)node * DD + c;
    if (node >= NN) {
        ushort4 z; z.x = 0; z.y = 0; z.z = 0; z.w = 0;
        *(ushort4*)dst = z;
        return;
    }
    int beg = rowptr[node], end = rowptr[node + 1];
    ushort4 hv = *(const ushort4*)(h16 + (size_t)node * DD + c);
    float4 acc;
    acc.x = h2f(hv.x); acc.y = h2f(hv.y); acc.z = h2f(hv.z); acc.w = h2f(hv.w);
    int j = beg;
    for (; j + 4 <= end; j += 4) {
        int s0 = csr[j], s1 = csr[j + 1], s2 = csr[j + 2], s3 = csr[j + 3];
        ushort4 v0 = *(const ushort4*)(h16 + (size_t)s0 * DD + c);
        ushort4 v1 = *(const ushort4*)(h16 + (size_t)s1 * DD + c);
        ushort4 v2 = *(const ushort4*)(h16 + (size_t)s2 * DD + c);
        ushort4 v3 = *(const ushort4*)(h16 + (size_t)s3 * DD + c);
        acc.x += h2f(v0.x) + h2f(v1.x) + h2f(v2.x) + h2f(v3.x);
        acc.y += h2f(v0.y) + h2f(v1.y) + h2f(v2.y) + h2f(v3.y);
        acc.z += h2f(v0.z) + h2f(v1.z) + h2f(v2.z) + h2f(v3.z);
        acc.w += h2f(v0.w) + h2f(v1.w) + h2f(v2.w) + h2f(v3.w);
    }
    for (; j < end; ++j) {
        int s0 = csr[j];
        ushort4 v0 = *(const ushort4*)(h16 + (size_t)s0 * DD + c);
        acc.x += h2f(v0.x); acc.y += h2f(v0.y); acc.z += h2f(v0.z); acc.w += h2f(v0.w);
    }
    ushort4 u;
    u.x = f2h(acc.x); u.y = f2h(acc.y); u.z = f2h(acc.z); u.w = f2h(acc.w);
    *(ushort4*)dst = u;
}

// =================== GEMM 128x256 tile, 8 waves (2x4), BK=32, fp16 MFMA ===================
// Epilogue: C(fp16) = acc + bias, fused fp32 column stats into sums.
#define GEMM_EPILOGUE(CPTR)                                                      \
    _Pragma("unroll")                                                            \
    for (int nf = 0; nf < 4; ++nf) {                                             \
        int col = wc * 64 + nf * 16 + l15;                                       \
        float bs = bias[col];                                                    \
        float s = 0.f, s2 = 0.f;                                                 \
        _Pragma("unroll")                                                        \
        for (int mf = 0; mf < 4; ++mf) {                                         \
            int r0 = mbase + wr * 64 + mf * 16 + l4 * 4;                         \
            _Pragma("unroll")                                                    \
            for (int j = 0; j < 4; ++j) {                                        \
                int row = r0 + j;                                                \
                if (row < NN) {                                                  \
                    float cv = acc[mf][nf][j] + bs;                              \
                    CPTR[(size_t)row * DD + col] = f2h(cv);                      \
                    s += cv; s2 += cv * cv;                                      \
                }                                                                \
            }                                                                    \
        }                                                                        \
        s  += __shfl_xor(s, 16);  s  += __shfl_xor(s, 32);                       \
        s2 += __shfl_xor(s2, 16); s2 += __shfl_xor(s2, 32);                      \
        if (l4 == 0) {                                                           \
            atomicAdd(&sums[col], s);                                            \
            atomicAdd(&sums[DD + col], s2);                                      \
        }                                                                        \
    }

// GEMM1: A fp16 (rb, zero-padded rows), t1 = A @ Wt^T + b ; stats fused
__global__ void gemm_f16_k(const unsigned short* __restrict__ A,
                           const unsigned short* __restrict__ Wt,
                           const float* __restrict__ bias,
                           unsigned short* __restrict__ C, float* __restrict__ sums) {
    __shared__ unsigned short As[128][40];
    __shared__ unsigned short Bs[256][40];
    const int tid   = threadIdx.x;
    const int mbase = blockIdx.x * 128;
    const int wave  = tid >> 6, lane = tid & 63;
    const int wr = wave >> 2, wc = wave & 3;
    const int l15 = lane & 15, l4 = lane >> 4;

    f32x4 acc[4][4] = {};

    for (int ks = 0; ks < 8; ++ks) {
        const int k0 = ks * 32;
        {
            int row = tid >> 2, seg = (tid & 3) * 8;
            uint4 wv = *(const uint4*)(A + (size_t)(mbase + row) * DD + k0 + seg);
            *(uint4*)&As[row][seg] = wv;
        }
        #pragma unroll
        for (int sI = 0; sI < 2; ++sI) {
            int q = sI * 512 + tid;
            int col = q >> 2, seg = (q & 3) * 8;
            uint4 wv = *(const uint4*)(Wt + (size_t)col * DD + k0 + seg);
            *(uint4*)&Bs[col][seg] = wv;
        }
        __syncthreads();

        half8 af[4], bf[4];
        #pragma unroll
        for (int mf = 0; mf < 4; ++mf)
            af[mf] = *(const half8*)&As[wr * 64 + mf * 16 + l15][l4 * 8];
        #pragma unroll
        for (int nf = 0; nf < 4; ++nf)
            bf[nf] = *(const half8*)&Bs[wc * 64 + nf * 16 + l15][l4 * 8];
        #pragma unroll
        for (int mf = 0; mf < 4; ++mf)
            #pragma unroll
            for (int nf = 0; nf < 4; ++nf)
                acc[mf][nf] = __builtin_amdgcn_mfma_f32_16x16x32_f16(
                    af[mf], bf[nf], acc[mf][nf], 0, 0, 0);
        __syncthreads();
    }
    GEMM_EPILOGUE(C)
}

// GEMM2: A fp16 (t1) with BN+ReLU applied at staging; t2 = relu(BN(A)) @ Wt^T + b
__global__ void gemm_bn_k(const unsigned short* __restrict__ A,
                          const unsigned short* __restrict__ Wt,
                          const float* __restrict__ bias,
                          const float* __restrict__ sc, const float* __restrict__ sh,
                          unsigned short* __restrict__ C, float* __restrict__ sums) {
    __shared__ unsigned short As[128][40];
    __shared__ unsigned short Bs[256][40];
    const int tid   = threadIdx.x;
    const int mbase = blockIdx.x * 128;
    const int wave  = tid >> 6, lane = tid & 63;
    const int wr = wave >> 2, wc = wave & 3;
    const int l15 = lane & 15, l4 = lane >> 4;

    f32x4 acc[4][4] = {};

    for (int ks = 0; ks < 8; ++ks) {
        const int k0 = ks * 32;
        // A: 128x32 fp16 -> BN+ReLU -> fp16; 512 threads x 16B
        {
            int row = tid >> 2, seg = (tid & 3) * 8;
            int grow = mbase + row;
            uint4 wv = {0u, 0u, 0u, 0u};
            if (grow < NN) wv = *(const uint4*)(A + (size_t)grow * DD + k0 + seg);
            unsigned short* ph = (unsigned short*)&wv;
            float4 a0 = *(const float4*)(sc + k0 + seg);
            float4 a1 = *(const float4*)(sc + k0 + seg + 4);
            float4 b0 = *(const float4*)(sh + k0 + seg);
            float4 b1 = *(const float4*)(sh + k0 + seg + 4);
            ushort4 u0, u1;
            u0.x = f2h(fmaxf(h2f(ph[0]) * a0.x + b0.x, 0.f));
            u0.y = f2h(fmaxf(h2f(ph[1]) * a0.y + b0.y, 0.f));
            u0.z = f2h(fmaxf(h2f(ph[2]) * a0.z + b0.z, 0.f));
            u0.w = f2h(fmaxf(h2f(ph[3]) * a0.w + b0.w, 0.f));
            u1.x = f2h(fmaxf(h2f(ph[4]) * a1.x + b1.x, 0.f));
            u1.y = f2h(fmaxf(h2f(ph[5]) * a1.y + b1.y, 0.f));
            u1.z = f2h(fmaxf(h2f(ph[6]) * a1.z + b1.z, 0.f));
            u1.w = f2h(fmaxf(h2f(ph[7]) * a1.w + b1.w, 0.f));
            *(ushort4*)&As[row][seg] = u0;
            *(ushort4*)&As[row][seg + 4] = u1;
        }
        #pragma unroll
        for (int sI = 0; sI < 2; ++sI) {
            int q = sI * 512 + tid;
            int col = q >> 2, seg = (q & 3) * 8;
            uint4 wv = *(const uint4*)(Wt + (size_t)col * DD + k0 + seg);
            *(uint4*)&Bs[col][seg] = wv;
        }
        __syncthreads();

        half8 af[4], bf[4];
        #pragma unroll
        for (int mf = 0; mf < 4; ++mf)
            af[mf] = *(const half8*)&As[wr * 64 + mf * 16 + l15][l4 * 8];
        #pragma unroll
        for (int nf = 0; nf < 4; ++nf)
            bf[nf] = *(const half8*)&Bs[wc * 64 + nf * 16 + l15][l4 * 8];
        #pragma unroll
        for (int mf = 0; mf < 4; ++mf)
            #pragma unroll
            for (int nf = 0; nf < 4; ++nf)
                acc[mf][nf] = __builtin_amdgcn_mfma_f32_16x16x32_f16(
                    af[mf], bf[nf], acc[mf][nf], 0, 0, 0);
        __syncthreads();
    }
    GEMM_EPILOGUE(C)
}

// ---- BN3 stats over m = relu(X*sc+sh), X fp16 ----
__global__ void bn_stats_k(const unsigned short* __restrict__ X,
                           const float* __restrict__ sc,
                           const float* __restrict__ sh, float* __restrict__ sums) {
    __shared__ float4 sA[256];
    __shared__ float4 sB[256];
    int t  = threadIdx.x;
    int rs = t >> 6;           // 0..3
    int c4 = t & 63;
    int c  = c4 * 4;
    float4 a = *(const float4*)(sc + c), b = *(const float4*)(sh + c);
    float4 s = {0.f,0.f,0.f,0.f}, s2 = {0.f,0.f,0.f,0.f};
    for (int r4 = blockIdx.x; r4 < NN / 4; r4 += gridDim.x) {
        int row = r4 * 4 + rs;
        ushort4 xu = *(const ushort4*)(X + (size_t)row * DD + c);
        float4 m;
        m.x = fmaxf(h2f(xu.x) * a.x + b.x, 0.f);
        m.y = fmaxf(h2f(xu.y) * a.y + b.y, 0.f);
        m.z = fmaxf(h2f(xu.z) * a.z + b.z, 0.f);
        m.w = fmaxf(h2f(xu.w) * a.w + b.w, 0.f);
        s.x += m.x; s.y += m.y; s.z += m.z; s.w += m.w;
        s2.x += m.x*m.x; s2.y += m.y*m.y; s2.z += m.z*m.z; s2.w += m.w*m.w;
    }
    sA[t] = s; sB[t] = s2;
    __syncthreads();
    if (t < 128) {
        sA[t].x += sA[t+128].x; sA[t].y += sA[t+128].y; sA[t].z += sA[t+128].z; sA[t].w += sA[t+128].w;
        sB[t].x += sB[t+128].x; sB[t].y += sB[t+128].y; sB[t].z += sB[t+128].z; sB[t].w += sB[t+128].w;
    }
    __syncthreads();
    if (t < 64) {
        float4 fs, fs2;
        fs.x = sA[t].x + sA[t+64].x; fs.y = sA[t].y + sA[t+64].y;
        fs.z = sA[t].z + sA[t+64].z; fs.w = sA[t].w + sA[t+64].w;
        fs2.x = sB[t].x + sB[t+64].x; fs2.y = sB[t].y + sB[t+64].y;
        fs2.z = sB[t].z + sB[t+64].z; fs2.w = sB[t].w + sB[t+64].w;
        atomicAdd(&sums[c + 0], fs.x);  atomicAdd(&sums[c + 1], fs.y);
        atomicAdd(&sums[c + 2], fs.z);  atomicAdd(&sums[c + 3], fs.w);
        atomicAdd(&sums[DD + c + 0], fs2.x); atomicAdd(&sums[DD + c + 1], fs2.y);
        atomicAdd(&sums[DD + c + 2], fs2.z); atomicAdd(&sums[DD + c + 3], fs2.w);
    }
}

// ---- finalize BN: scale/shift from sums; re-zero sums ----
__global__ void fin_k(float* __restrict__ sums, const float* __restrict__ g,
                      const float* __restrict__ b, float* __restrict__ sc,
                      float* __restrict__ sh) {
    int c = threadIdx.x;
    float s = sums[c], s2 = sums[DD + c];
    float mu  = s * (1.f / NN);
    float var = s2 * (1.f / NN) - mu * mu;
    float rstd = rsqrtf(var + 1e-5f);
    float a = rstd * g[c];
    sc[c] = a;
    sh[c] = b[c] - mu * a;
    sums[c] = 0.f; sums[DD + c] = 0.f;
}

// ---- final apply: h = relu(BN3(relu(BN2(t2)))); write out (fp32) + h16 (fp16) ----
__global__ void final_k(const unsigned short* __restrict__ T2,
                        const float* __restrict__ sc2, const float* __restrict__ sh2,
                        const float* __restrict__ sc3, const float* __restrict__ sh3,
                        float4* __restrict__ Out, unsigned short* __restrict__ h16,
                        int loff4) {
    int i = blockIdx.x * 256 + threadIdx.x;   // over NN*64
    int row = i >> 6, c4 = i & 63;
    int c = c4 * 4;
    ushort4 xu = *(const ushort4*)(T2 + (size_t)i * 4);
    float4 a2 = *(const float4*)(sc2 + c), b2 = *(const float4*)(sh2 + c);
    float4 a3 = *(const float4*)(sc3 + c), b3 = *(const float4*)(sh3 + c);
    float4 m, h;
    m.x = fmaxf(h2f(xu.x) * a2.x + b2.x, 0.f);
    m.y = fmaxf(h2f(xu.y) * a2.y + b2.y, 0.f);
    m.z = fmaxf(h2f(xu.z) * a2.z + b2.z, 0.f);
    m.w = fmaxf(h2f(xu.w) * a2.w + b2.w, 0.f);
    h.x = fmaxf(m.x * a3.x + b3.x, 0.f);
    h.y = fmaxf(m.y * a3.y + b3.y, 0.f);
    h.z = fmaxf(m.z * a3.z + b3.z, 0.f);
    h.w = fmaxf(m.w * a3.w + b3.w, 0.f);
    Out[(size_t)row * 256 + loff4 + c4] = h;
    ushort4 u;
    u.x = f2h(h.x); u.y = f2h(h.y); u.z = f2h(h.z); u.w = f2h(h.w);
    *(ushort4*)(h16 + (size_t)i * 4) = u;
}

extern "C" void kernel_launch(void* const* d_in, const int* in_sizes, int n_in,
                              void* d_out, int out_size, void* d_ws, size_t ws_size,
                              hipStream_t stream) {
    const float* h_in = (const float*)d_in[0];
    const int*   ei   = (const int*)d_in[1];
    const float* W1   = (const float*)d_in[2];
    const float* b1   = (const float*)d_in[3];
    const float* W2   = (const float*)d_in[4];
    const float* b2   = (const float*)d_in[5];
    const float* g1   = (const float*)d_in[6];
    const float* bb1  = (const float*)d_in[7];
    const float* g2   = (const float*)d_in[8];
    const float* bb2  = (const float*)d_in[9];
    const float* g3   = (const float*)d_in[10];
    const float* bb3  = (const float*)d_in[11];
    float* out = (float*)d_out;

    const size_t SZ = (size_t)NN * DD;
    unsigned short* t1  = (unsigned short*)d_ws;               // NN*DD fp16
    unsigned short* t2  = t1 + SZ;                             // NN*DD fp16
    unsigned short* rb  = t2 + SZ;                             // NPAD*DD fp16
    unsigned short* h16 = rb + (size_t)NPAD * DD;              // NN*DD fp16
    unsigned short* Wt1 = h16 + SZ;
    unsigned short* Wt2 = Wt1 + (size_t)NL * DD * DD;
    float* sums = (float*)(Wt2 + (size_t)NL * DD * DD);        // 512
    float* sc1 = sums + 512; float* sh1 = sc1 + DD;
    float* sc2 = sh1 + DD;   float* sh2 = sc2 + DD;
    float* sc3 = sh2 + DD;   float* sh3 = sc3 + DD;
    int* deg    = (int*)(sh3 + DD);
    int* bsum   = deg + NN;          // 196 (pad 256)
    int* boff   = bsum + 256;        // 256
    int* rowptr = boff + 256;        // NN+1
    int* cursor = rowptr + NN + 1;   // NN
    int* csr    = cursor + NN;       // NE

    // one-time setup
    zero_k<<<1, 512, 0, stream>>>(sums);
    wconv_k<<<1024, 256, 0, stream>>>(W1, Wt1);
    wconv_k<<<1024, 256, 0, stream>>>(W2, Wt2);
    h16conv_k<<<12500, 256, 0, stream>>>((const float4*)h_in, h16);
    zdeg_k<<<196, 256, 0, stream>>>(deg);
    hist_k<<<(NE + 255) / 256, 256, 0, stream>>>(ei, deg);
    bsum_k<<<196, 256, 0, stream>>>(deg, bsum);
    bscan_k<<<1, 256, 0, stream>>>(bsum, boff);
    rowptr_k<<<196, 256, 0, stream>>>(deg, boff, rowptr, cursor);
    fill_k<<<(NE + 255) / 256, 256, 0, stream>>>(ei, cursor, csr);

    for (int i = 0; i < NL; ++i) {
        gather_k<<<NPAD / 4, 256, 0, stream>>>(rowptr, csr, h16, rb);

        gemm_f16_k<<<391, 512, 0, stream>>>(
            rb, Wt1 + (size_t)i * DD * DD, b1 + (size_t)i * DD, t1, sums);
        fin_k<<<1, 256, 0, stream>>>(sums, g1 + (size_t)i * DD, bb1 + (size_t)i * DD, sc1, sh1);

        gemm_bn_k<<<391, 512, 0, stream>>>(
            t1, Wt2 + (size_t)i * DD * DD, b2 + (size_t)i * DD, sc1, sh1, t2, sums);
        fin_k<<<1, 256, 0, stream>>>(sums, g2 + (size_t)i * DD, bb2 + (size_t)i * DD, sc2, sh2);

        bn_stats_k<<<500, 256, 0, stream>>>(t2, sc2, sh2, sums);
        fin_k<<<1, 256, 0, stream>>>(sums, g3 + (size_t)i * DD, bb3 + (size_t)i * DD, sc3, sh3);

        final_k<<<12500, 256, 0, stream>>>(t2, sc2, sh2, sc3, sh3,
                                           (float4*)out, h16, i * 64);
    }
}